// Round 12
// baseline (76.406 us; speedup 1.0000x reference)
//
#include <hip/hip_runtime.h>
#include <stdint.h>

typedef float f32x2 __attribute__((ext_vector_type(2)));
typedef float f32x4 __attribute__((ext_vector_type(4)));

#define TILE_F 19840      // 64 rows x 310 floats
#define NTPB   4          // tiles per block
#define PSTR   80         // h1-partial stride (dwords), 16B-aligned rows
#define CP_OFF 5120       // coeff-partial region [5120, 6144)
#define CPSTR  16         // 16 floats per row: 8 waves x f32x2
#define A_F    6144       // split: A=[0,6144) scratch-aliased (staged late)
#define BPW    1712       // B floats per wave-eighth (14464/8)
#define APW    768        // A floats per wave-eighth (6144/8)
#define LDSF   (TILE_F + 128)
#define LDS_BYTES (LDSF * 4)    // 79,872 B -> 2 blocks/CU (16 waves/CU)

__device__ __forceinline__ float leaky(float v) { return fmaxf(v, 0.01f * v); }
__device__ __forceinline__ f32x2 leaky2(f32x2 v) {
    return __builtin_elementwise_max(v, v * 0.01f);
}

// global->LDS direct, 16 B/lane (1 KB per wave-instr); cannot be sunk by the
// compiler past the volatile waitcnt/barrier asm (side-effecting).
__device__ __forceinline__ void gload16(const float* g, float* l) {
    auto gp = reinterpret_cast<const float __attribute__((address_space(1)))*>(
        reinterpret_cast<uintptr_t>(g));
    auto lp = reinterpret_cast<float __attribute__((address_space(3)))*>(
        reinterpret_cast<uintptr_t>(l));
    __builtin_amdgcn_global_load_lds(gp, lp, 16, 0, 0);
}

// Region B (rows ~20-63): 1712 floats/wave = 6 full w16 + 704B tail (44 lanes)
__device__ __forceinline__ void stage_B(const float* src, float* dst, int lane) {
    #pragma unroll
    for (int i = 0; i < 6; ++i) gload16(src + i * 256, dst + i * 256);
    if (lane < 44) gload16(src + 6 * 256, dst + 6 * 256);
}
// Region A (rows 0-19 + scratch alias): 768 floats/wave = 3 full w16
__device__ __forceinline__ void stage_A(const float* src, float* dst) {
    #pragma unroll
    for (int i = 0; i < 3; ++i) gload16(src + i * 256, dst + i * 256);
}

// FMA of KQ k's (xk in VGPRs) vs W1 slice broadcast from SGPRs (s_load).
template<int KQ>
__device__ __forceinline__ void fma_xk(const float* xk, const float* __restrict__ Wb,
                                       float* acc) {
    #pragma unroll
    for (int k = 0; k < KQ; ++k) {
        #pragma unroll
        for (int j = 0; j < 10; ++j)
            acc[j] = fmaf(xk[k], Wb[k * 10 + j], acc[j]);
    }
}

__global__ __launch_bounds__(512, 4) void gen_mlp_r12(
    const float* __restrict__ x, const float* __restrict__ data_t,
    const float* __restrict__ W1, const float* __restrict__ b1,
    const float* __restrict__ W2, const float* __restrict__ b2,
    const float* __restrict__ W3, const float* __restrict__ b3,
    float* __restrict__ out)
{
    extern __shared__ float lds[];
    float* buf = lds;                 // x tile; A-region doubles as scratch
    float* ccs = lds + TILE_F;        // 128 floats: final (c0,c1) per row

    const int t    = threadIdx.x;
    const int lane = t & 63;
    const int row  = lane;                                    // lane = row
    const int wq   = __builtin_amdgcn_readfirstlane(t >> 6);  // wave 0..7

    const int tile0 = blockIdx.x * NTPB;

    // ---- prologue: stage tile0 fully (async, zero VGPR) ----
    {
        const float* g = x + (size_t)tile0 * TILE_F;
        stage_A(g + wq * APW + lane * 4,       buf + wq * APW);
        stage_B(g + A_F + wq * BPW + lane * 4, buf + A_F + wq * BPW, lane);
    }
    asm volatile("s_waitcnt vmcnt(0)" ::: "memory");
    __builtin_amdgcn_s_barrier();

    #pragma unroll 1
    for (int it = 0; it < NTPB; ++it) {
        const int tile = tile0 + it;
        const bool pf  = (it + 1 < NTPB);
        const float* gnext = x + (size_t)(tile + 1) * TILE_F;

        // ---- data_t loads FIRST (oldest vm ops: their wait won't drain stages)
        const f32x4* dt4 = (const f32x4*)data_t + (size_t)tile * 1600;
        f32x4 tv0 = dt4[t], tv1 = dt4[512 + t], tv2 = dt4[1024 + t], tv3;
        if (t < 64) tv3 = dt4[1536 + t];

        // ---- x: my k-eighth -> registers (whole tile collectively consumed)
        float xk[40];
        {
            const float* xr = buf + row * 310 + wq * 40;
            if (wq == 7) {
                #pragma unroll
                for (int q = 0; q < 15; ++q)
                    *(f32x2*)&xk[2 * q] = *(const f32x2*)(xr + 2 * q);
            } else {
                #pragma unroll
                for (int q = 0; q < 20; ++q)
                    *(f32x2*)&xk[2 * q] = *(const f32x2*)(xr + 2 * q);
            }
        }
        asm volatile("s_waitcnt lgkmcnt(0)" ::: "memory");
        __builtin_amdgcn_s_barrier();     // (a0): buf free (x lives in regs)

        // ---- stage next tile's B region NOW: in flight across L1+L2 compute
        if (pf) stage_B(gnext + A_F + wq * BPW + lane * 4, buf + A_F + wq * BPW, lane);

        // ---- L1: my k-eighth, weights via s_load (SGPR broadcast) ----
        float acc[10] = {0,0,0,0,0,0,0,0,0,0};
        if (wq == 7) fma_xk<30>(xk, W1 + 2800, acc);
        else         fma_xk<40>(xk, W1 + wq * 400, acc);

        {   // ---- h1 partials [row][wq][10] into A-region scratch ----
            float* pw = buf + row * PSTR + wq * 10;
            #pragma unroll
            for (int j = 0; j < 5; ++j)
                *(f32x2*)(pw + 2 * j) = (f32x2){acc[2 * j], acc[2 * j + 1]};
        }
        asm volatile("s_waitcnt lgkmcnt(0)" ::: "memory");
        __builtin_amdgcn_s_barrier();     // (a)

        // ---- h1 = leaky(sum of 8 partials + b1), low-reg b64 window ----
        float h1[10];
        {
            const float* pr = buf + row * PSTR;
            float s[10];
            #pragma unroll
            for (int j = 0; j < 10; ++j) s[j] = b1[j];
            #pragma unroll
            for (int sl = 0; sl < 8; ++sl) {
                #pragma unroll
                for (int m = 0; m < 5; ++m) {
                    f32x2 v = *(const f32x2*)(pr + sl * 10 + 2 * m);
                    s[2 * m]     += v.x;
                    s[2 * m + 1] += v.y;
                }
            }
            #pragma unroll
            for (int j = 0; j < 10; ++j) h1[j] = leaky(s[j]);
        }

        // ---- L2 j-slice (16 outs) + L3 partial; weights via s_load ----
        float hh[16];
        #pragma unroll
        for (int jj = 0; jj < 16; ++jj) hh[jj] = b2[wq * 16 + jj];
        #pragma unroll
        for (int k = 0; k < 10; ++k) {
            #pragma unroll
            for (int jj = 0; jj < 16; ++jj)
                hh[jj] = fmaf(h1[k], W2[k * 128 + wq * 16 + jj], hh[jj]);
        }
        f32x2 p = {0.f, 0.f};
        #pragma unroll
        for (int jj = 0; jj < 16; ++jj) {
            const float s = leaky(hh[jj]);
            p.x = fmaf(s, W3[(wq * 16 + jj) * 2 + 0], p.x);
            p.y = fmaf(s, W3[(wq * 16 + jj) * 2 + 1], p.y);
        }

        // ---- coeff partials [row][16] at CP_OFF (inside A region) ----
        *(f32x2*)(buf + CP_OFF + row * CPSTR + 2 * wq) = p;
        asm volatile("s_waitcnt lgkmcnt(0)" ::: "memory");
        __builtin_amdgcn_s_barrier();     // (b)

        if (wq == 0) {   // 4 x b128, 16B-aligned
            const float* cb = buf + CP_OFF + row * CPSTR;
            f32x2 q = {b3[0], b3[1]};
            #pragma unroll
            for (int i = 0; i < 4; ++i) {
                f32x4 v = *(const f32x4*)(cb + 4 * i);
                q.x += v[0] + v[2];
                q.y += v[1] + v[3];
            }
            *(f32x2*)(ccs + 2 * row) = leaky2(q);
        }
        asm volatile("s_waitcnt lgkmcnt(0)" ::: "memory");
        __builtin_amdgcn_s_barrier();     // (b2): ccs ready, A-scratch dead

        // ---- stage next tile's A region (scratch is dead now) ----
        if (pf) stage_A(gnext + wq * APW + lane * 4, buf + wq * APW);

        // ---- epilogue: out = t*(c0 + c1*t) ----
        f32x4* o4 = (f32x4*)out + (size_t)tile * 1600;
        {
            f32x2 cc = *(const f32x2*)(ccs + 2 * (t / 25));
            o4[t] = tv0 * (tv0 * cc.y + cc.x);
        }
        {
            const int idx = 512 + t;
            f32x2 cc = *(const f32x2*)(ccs + 2 * (idx / 25));
            o4[idx] = tv1 * (tv1 * cc.y + cc.x);
        }
        {
            const int idx = 1024 + t;
            f32x2 cc = *(const f32x2*)(ccs + 2 * (idx / 25));
            o4[idx] = tv2 * (tv2 * cc.y + cc.x);
        }
        if (t < 64) {
            const int idx = 1536 + t;
            f32x2 cc = *(const f32x2*)(ccs + 2 * (idx / 25));
            o4[idx] = tv3 * (tv3 * cc.y + cc.x);
        }

        // ---- (d): stages of tile it+1 done; let the 4 stores ride ----
        if (pf) {
            asm volatile("s_waitcnt vmcnt(4)" ::: "memory");
            __builtin_amdgcn_s_barrier();
        }
    }
}

extern "C" void kernel_launch(void* const* d_in, const int* in_sizes, int n_in,
                              void* d_out, int out_size, void* d_ws, size_t ws_size,
                              hipStream_t stream) {
    const float* x      = (const float*)d_in[0];
    const float* data_t = (const float*)d_in[1];
    const float* W1     = (const float*)d_in[2];
    const float* b1     = (const float*)d_in[3];
    const float* W2     = (const float*)d_in[4];
    const float* b2     = (const float*)d_in[5];
    const float* W3     = (const float*)d_in[6];
    const float* b3     = (const float*)d_in[7];
    float* out = (float*)d_out;

    hipFuncSetAttribute((const void*)gen_mlp_r12,
                        hipFuncAttributeMaxDynamicSharedMemorySize, LDS_BYTES);
    // 512 blocks x 512 threads x 4 tiles of 64 rows = 131072 rows; 2 blocks/CU
    gen_mlp_r12<<<512, 512, LDS_BYTES, stream>>>(x, data_t, W1, b1, W2, b2, W3, b3, out);
}

// Round 14
// 60.319 us; speedup vs baseline: 1.2667x; 1.2667x over previous
//
#include <hip/hip_runtime.h>
#include <stdint.h>

typedef float f32x2 __attribute__((ext_vector_type(2)));
typedef float f32x4 __attribute__((ext_vector_type(4)));

#define TILE_F 19840      // 64 rows x 310 floats
#define NTPB   4          // tiles per block
#define PSTR   82         // partial stride: >=80, even, 82%32=18 (gcd 2 -> 16 banks)
#define CP_OFF 5248       // = 64*PSTR; coeff partials [5248, 6400)
#define CPSTR  18         // 18%32 -> 16 banks
#define A_F    8192       // A region [0,8192): scratch-aliased, staged late
#define APW    1024       // A floats per wave-eighth = 4 full w16 instrs
#define BPW    1456       // B floats per wave-eighth = 5 full + 176 tail
#define LDSF   (TILE_F + 128)
#define LDS_BYTES (LDSF * 4)    // 79,872 B -> 2 blocks/CU (16 waves/CU)

__device__ __forceinline__ float leaky(float v) { return fmaxf(v, 0.01f * v); }
__device__ __forceinline__ f32x2 leaky2(f32x2 v) {
    return __builtin_elementwise_max(v, v * 0.01f);
}

// global->LDS direct, 16 B/lane (1 KB per wave-instr); side-effecting, cannot
// be sunk past the volatile waitcnt/barrier asm.
__device__ __forceinline__ void gload16(const float* g, float* l) {
    auto gp = reinterpret_cast<const float __attribute__((address_space(1)))*>(
        reinterpret_cast<uintptr_t>(g));
    auto lp = reinterpret_cast<float __attribute__((address_space(3)))*>(
        reinterpret_cast<uintptr_t>(l));
    __builtin_amdgcn_global_load_lds(gp, lp, 16, 0, 0);
}

// Region B: 1456 floats/wave = 5 full w16 + 704B tail (44 lanes)
__device__ __forceinline__ void stage_B(const float* src, float* dst, int lane) {
    #pragma unroll
    for (int i = 0; i < 5; ++i) gload16(src + i * 256, dst + i * 256);
    if (lane < 44) gload16(src + 5 * 256, dst + 5 * 256);
}
// Region A: 1024 floats/wave = 4 full w16 (no tail)
__device__ __forceinline__ void stage_A(const float* src, float* dst) {
    #pragma unroll
    for (int i = 0; i < 4; ++i) gload16(src + i * 256, dst + i * 256);
}

// FMA of KQ k's (xk in VGPRs) vs W1 slice broadcast from SGPRs (s_load).
template<int KQ>
__device__ __forceinline__ void fma_xk(const float* xk, const float* __restrict__ Wb,
                                       float* acc) {
    #pragma unroll
    for (int k = 0; k < KQ; ++k) {
        #pragma unroll
        for (int j = 0; j < 10; ++j)
            acc[j] = fmaf(xk[k], Wb[k * 10 + j], acc[j]);
    }
}

__global__ __launch_bounds__(512, 4) void gen_mlp_r14(
    const float* __restrict__ x, const float* __restrict__ data_t,
    const float* __restrict__ W1, const float* __restrict__ b1,
    const float* __restrict__ W2, const float* __restrict__ b2,
    const float* __restrict__ W3, const float* __restrict__ b3,
    float* __restrict__ out)
{
    extern __shared__ float lds[];
    float* buf = lds;                 // x tile; A-region doubles as scratch
    float* ccs = lds + TILE_F;        // 128 floats: final (c0,c1) per row

    const int t    = threadIdx.x;
    const int lane = t & 63;
    const int row  = lane;                                    // lane = row
    const int wq   = __builtin_amdgcn_readfirstlane(t >> 6);  // wave 0..7

    const int tile0 = blockIdx.x * NTPB;

    // ---- prologue: stage tile0 fully (async, zero VGPR) ----
    {
        const float* g = x + (size_t)tile0 * TILE_F;
        stage_A(g + wq * APW + lane * 4,       buf + wq * APW);
        stage_B(g + A_F + wq * BPW + lane * 4, buf + A_F + wq * BPW, lane);
    }
    asm volatile("s_waitcnt vmcnt(0)" ::: "memory");
    __builtin_amdgcn_s_barrier();

    #pragma unroll 1
    for (int it = 0; it < NTPB; ++it) {
        const int tile  = tile0 + it;
        // unconditional staging (static vm-op counts -> exact compiler waits);
        // last iteration re-stages tile0 (L3-warm, harmless).
        const int tnext = (it + 1 < NTPB) ? tile + 1 : tile0;
        const float* gnext = x + (size_t)tnext * TILE_F;

        // ---- data_t loads FIRST (oldest vm ops of the iteration) ----
        const f32x4* dt4 = (const f32x4*)data_t + (size_t)tile * 1600;
        f32x4 tv0 = dt4[t], tv1 = dt4[512 + t], tv2 = dt4[1024 + t], tv3;
        if (t < 64) tv3 = dt4[1536 + t];

        // ---- x: my k-eighth -> registers ----
        float xk[40];
        {
            const float* xr = buf + row * 310 + wq * 40;
            if (wq == 7) {
                #pragma unroll
                for (int q = 0; q < 15; ++q)
                    *(f32x2*)&xk[2 * q] = *(const f32x2*)(xr + 2 * q);
            } else {
                #pragma unroll
                for (int q = 0; q < 20; ++q)
                    *(f32x2*)&xk[2 * q] = *(const f32x2*)(xr + 2 * q);
            }
        }
        asm volatile("s_waitcnt lgkmcnt(0)" ::: "memory");
        __builtin_amdgcn_s_barrier();     // (a0): buf free (x lives in regs)

        // ---- stage next tile's B region: in flight across L1+L2 compute ----
        stage_B(gnext + A_F + wq * BPW + lane * 4, buf + A_F + wq * BPW, lane);

        // ---- L1: my k-eighth, weights via s_load (SGPR broadcast) ----
        float acc[10] = {0,0,0,0,0,0,0,0,0,0};
        if (wq == 7) fma_xk<30>(xk, W1 + 2800, acc);
        else         fma_xk<40>(xk, W1 + wq * 400, acc);

        {   // ---- h1 partials [row][wq][10] into A-region scratch ----
            float* pw = buf + row * PSTR + wq * 10;
            #pragma unroll
            for (int j = 0; j < 5; ++j)
                *(f32x2*)(pw + 2 * j) = (f32x2){acc[2 * j], acc[2 * j + 1]};
        }
        asm volatile("s_waitcnt lgkmcnt(0)" ::: "memory");
        __builtin_amdgcn_s_barrier();     // (a)

        // ---- h1 = leaky(sum of 8 partials + b1) ----
        float h1[10];
        {
            const float* pr = buf + row * PSTR;
            float s[10];
            #pragma unroll
            for (int j = 0; j < 10; ++j) s[j] = b1[j];
            #pragma unroll
            for (int sl = 0; sl < 8; ++sl) {
                #pragma unroll
                for (int m = 0; m < 5; ++m) {
                    f32x2 v = *(const f32x2*)(pr + sl * 10 + 2 * m);
                    s[2 * m]     += v.x;
                    s[2 * m + 1] += v.y;
                }
            }
            #pragma unroll
            for (int j = 0; j < 10; ++j) h1[j] = leaky(s[j]);
        }

        // ---- L2 j-slice (16 outs) + L3 partial; weights via s_load ----
        float hh[16];
        #pragma unroll
        for (int jj = 0; jj < 16; ++jj) hh[jj] = b2[wq * 16 + jj];
        #pragma unroll
        for (int k = 0; k < 10; ++k) {
            #pragma unroll
            for (int jj = 0; jj < 16; ++jj)
                hh[jj] = fmaf(h1[k], W2[k * 128 + wq * 16 + jj], hh[jj]);
        }
        f32x2 p = {0.f, 0.f};
        #pragma unroll
        for (int jj = 0; jj < 16; ++jj) {
            const float s = leaky(hh[jj]);
            p.x = fmaf(s, W3[(wq * 16 + jj) * 2 + 0], p.x);
            p.y = fmaf(s, W3[(wq * 16 + jj) * 2 + 1], p.y);
        }

        // ---- coeff partials [row][18] at CP_OFF (disjoint from h1 partials) ----
        *(f32x2*)(buf + CP_OFF + row * CPSTR + 2 * wq) = p;
        asm volatile("s_waitcnt lgkmcnt(0)" ::: "memory");
        __builtin_amdgcn_s_barrier();     // (b)

        if (wq == 0) {   // 8 x b64 reads, 16-bank spread
            const float* cb = buf + CP_OFF + row * CPSTR;
            f32x2 q = {b3[0], b3[1]};
            #pragma unroll
            for (int i = 0; i < 8; ++i) {
                f32x2 v = *(const f32x2*)(cb + 2 * i);
                q.x += v.x;
                q.y += v.y;
            }
            *(f32x2*)(ccs + 2 * row) = leaky2(q);
        }
        asm volatile("s_waitcnt lgkmcnt(0)" ::: "memory");
        __builtin_amdgcn_s_barrier();     // (b2): ccs ready, A-scratch dead

        // ---- stage next tile's A region (scratch is dead now) ----
        stage_A(gnext + wq * APW + lane * 4, buf + wq * APW);

        // ---- epilogue: out = t*(c0 + c1*t) ----
        f32x4* o4 = (f32x4*)out + (size_t)tile * 1600;
        {
            f32x2 cc = *(const f32x2*)(ccs + 2 * (t / 25));
            o4[t] = tv0 * (tv0 * cc.y + cc.x);
        }
        {
            const int idx = 512 + t;
            f32x2 cc = *(const f32x2*)(ccs + 2 * (idx / 25));
            o4[idx] = tv1 * (tv1 * cc.y + cc.x);
        }
        {
            const int idx = 1024 + t;
            f32x2 cc = *(const f32x2*)(ccs + 2 * (idx / 25));
            o4[idx] = tv2 * (tv2 * cc.y + cc.x);
        }
        if (t < 64) {
            const int idx = 1536 + t;
            f32x2 cc = *(const f32x2*)(ccs + 2 * (idx / 25));
            o4[idx] = tv3 * (tv3 * cc.y + cc.x);
        }

        // ---- (d): all 10 staging ops of tile it+1 retired; 3 stores ride ----
        asm volatile("s_waitcnt vmcnt(3)" ::: "memory");
        __builtin_amdgcn_s_barrier();
    }
}

extern "C" void kernel_launch(void* const* d_in, const int* in_sizes, int n_in,
                              void* d_out, int out_size, void* d_ws, size_t ws_size,
                              hipStream_t stream) {
    const float* x      = (const float*)d_in[0];
    const float* data_t = (const float*)d_in[1];
    const float* W1     = (const float*)d_in[2];
    const float* b1     = (const float*)d_in[3];
    const float* W2     = (const float*)d_in[4];
    const float* b2     = (const float*)d_in[5];
    const float* W3     = (const float*)d_in[6];
    const float* b3     = (const float*)d_in[7];
    float* out = (float*)d_out;

    hipFuncSetAttribute((const void*)gen_mlp_r14,
                        hipFuncAttributeMaxDynamicSharedMemorySize, LDS_BYTES);
    // 512 blocks x 512 threads x 4 tiles of 64 rows = 131072 rows; 2 blocks/CU
    gen_mlp_r14<<<512, 512, LDS_BYTES, stream>>>(x, data_t, W1, b1, W2, b2, W3, b3, out);
}